// Round 13
// baseline (142.618 us; speedup 1.0000x reference)
//
#include <hip/hip_runtime.h>
#include <cstddef>

// ----------------------------------------------------------------------------
// AttentionFusion round 13: 7 launches. scores reverted to the PROVEN round-2
// geometry (block=(n,b,t8): 4 waves lockstep on ONE py panel -> L1 sharing,
// 21us measured). Context unfused (probs->ctx f32 only). FFN1 is split-A
// ([speech|ctx] f32, staged AF32) so `fused` is never materialized.
// Measured ladder: same-panel scores 21us vs per-wave-panel 48-53us.
// ----------------------------------------------------------------------------

#define D_  768
#define HD_ 768
#define NH_ 4
#define B_  4
#define T1_ 128
#define T2_ 128
#define M_  (B_*T1_)
#define LN_EPS_ 1e-5f

typedef unsigned short u16;
typedef unsigned int u32;
typedef _Float16 f16;
typedef _Float16 f16x2 __attribute__((ext_vector_type(2)));
typedef __bf16 bf16x8 __attribute__((ext_vector_type(8)));
typedef float f32x4 __attribute__((ext_vector_type(4)));

__device__ __forceinline__ u16 f2bf(float f) {
    union { float f; unsigned int u; } v; v.f = f;
    unsigned int u = v.u + (0x7FFFu + ((v.u >> 16) & 1u));
    return (u16)(u >> 16);
}
__device__ __forceinline__ u32 pack_bf2(float lo, float hi) {
    return (u32)f2bf(lo) | ((u32)f2bf(hi) << 16);
}
__device__ __forceinline__ u16 f16bits(f16 h) {
    return __builtin_bit_cast(unsigned short, h);
}
__device__ __forceinline__ f16x2 bcast2(u32 u) {
    return __builtin_bit_cast(f16x2, u);
}
__device__ __forceinline__ u32 splat2(u16 h) { return (u32)h * 0x10001u; }

// ---------------- bf16 MFMA GEMM: C[M,N] = A[M,K] @ Bt[N,K]^T + bias --------
// AF32: A is f32 (bf16-converted during staging). SPLIT: A=[A1 k<768|A2 k>=768].
// MODE: 0 = f32 rows, 1 = bf16 rows, 2 = f16 rows, 3 = f16 transposed (py_t)
template<bool RELU, int MODE, bool AF32, bool SPLIT>
__device__ __forceinline__ void gemm_mfma_body(
    const void* __restrict__ Av1, const void* __restrict__ Av2, int lda,
    const u16* __restrict__ Bt, int ldb,
    const float* __restrict__ bias,
    void* __restrict__ C, int ldc, int K, int m0, int n0)
{
    __shared__ __align__(16) u16 As[64][40];
    __shared__ __align__(16) u16 Bs[64][40];
    __shared__ u16 Ts[MODE == 3 ? 64 : 1][MODE == 3 ? 68 : 1];

    const int tid = threadIdx.x;
    const int row = tid >> 2;
    const int kq  = (tid & 3) << 3;
    const int lane = tid & 63;
    const int w  = tid >> 6;
    const int wr = (w >> 1) << 5;
    const int wc = (w & 1) << 5;
    const int l16 = lane & 15;
    const int lk8 = (lane >> 4) << 3;
    const int r4  = (lane >> 4) << 2;

    const u16*   aptr16  = (const u16*)Av1 + (size_t)(m0 + row) * lda + kq;
    const float* aptrf1  = (const float*)Av1 + (size_t)(m0 + row) * lda + kq;
    const float* aptrf2  = SPLIT ? ((const float*)Av2 + (size_t)(m0 + row) * lda + kq) : nullptr;
    const u16*   bptr    = Bt + (size_t)(n0 + row) * ldb + kq;

    f32x4 acc00 = {0.f,0.f,0.f,0.f}, acc01 = {0.f,0.f,0.f,0.f};
    f32x4 acc10 = {0.f,0.f,0.f,0.f}, acc11 = {0.f,0.f,0.f,0.f};

    auto loadA = [&](int k0) -> uint4 {
        if (AF32) {
            const float* base = aptrf1;
            int kk = k0;
            if (SPLIT && k0 >= 768) { base = aptrf2; kk = k0 - 768; }
            float4 ax = *(const float4*)(base + kk);
            float4 ay = *(const float4*)(base + kk + 4);
            uint4 r;
            r.x = pack_bf2(ax.x, ax.y); r.y = pack_bf2(ax.z, ax.w);
            r.z = pack_bf2(ay.x, ay.y); r.w = pack_bf2(ay.z, ay.w);
            return r;
        }
        return *(const uint4*)(aptr16 + k0);
    };

    uint4 a_nxt = loadA(0);
    uint4 b_nxt = *(const uint4*)bptr;

    for (int k0 = 0; k0 < K; k0 += 32) {
        __syncthreads();
        *(uint4*)&As[row][kq] = a_nxt;
        *(uint4*)&Bs[row][kq] = b_nxt;
        if (k0 + 32 < K) {
            a_nxt = loadA(k0 + 32);
            b_nxt = *(const uint4*)(bptr + k0 + 32);
        }
        __syncthreads();
        bf16x8 af0 = *(const bf16x8*)&As[wr + l16][lk8];
        bf16x8 af1 = *(const bf16x8*)&As[wr + 16 + l16][lk8];
        bf16x8 bf0 = *(const bf16x8*)&Bs[wc + l16][lk8];
        bf16x8 bf1 = *(const bf16x8*)&Bs[wc + 16 + l16][lk8];
        acc00 = __builtin_amdgcn_mfma_f32_16x16x32_bf16(af0, bf0, acc00, 0, 0, 0);
        acc01 = __builtin_amdgcn_mfma_f32_16x16x32_bf16(af0, bf1, acc01, 0, 0, 0);
        acc10 = __builtin_amdgcn_mfma_f32_16x16x32_bf16(af1, bf0, acc10, 0, 0, 0);
        acc11 = __builtin_amdgcn_mfma_f32_16x16x32_bf16(af1, bf1, acc11, 0, 0, 0);
    }

#define EPI_FRAG(ACC, MF, NF)                                                  \
    {                                                                          \
        const int gcol = n0 + wc + (NF)*16 + l16;                              \
        const float bv = bias ? bias[gcol] : 0.f;                              \
        float v_[4];                                                           \
        _Pragma("unroll")                                                      \
        for (int r = 0; r < 4; r++) {                                          \
            float v = ACC[r] + bv;                                             \
            if (RELU) v = fmaxf(v, 0.f);                                       \
            v_[r] = v;                                                         \
        }                                                                      \
        const int lr0 = wr + (MF)*16 + r4;                                     \
        if (MODE == 3) {                                                       \
            const int lc = wc + (NF)*16 + l16;                                 \
            _Pragma("unroll")                                                  \
            for (int r = 0; r < 4; r++) Ts[lc][lr0 + r] = f16bits((f16)v_[r]); \
        } else {                                                               \
            _Pragma("unroll")                                                  \
            for (int r = 0; r < 4; r++) {                                      \
                const size_t off = (size_t)(m0 + lr0 + r) * ldc + gcol;        \
                if (MODE == 0) ((float*)C)[off] = v_[r];                       \
                else if (MODE == 1) ((u16*)C)[off] = f2bf(v_[r]);              \
                else ((u16*)C)[off] = f16bits((f16)v_[r]);                     \
            }                                                                  \
        }                                                                      \
    }
    EPI_FRAG(acc00, 0, 0) EPI_FRAG(acc01, 0, 1)
    EPI_FRAG(acc10, 1, 0) EPI_FRAG(acc11, 1, 1)
#undef EPI_FRAG

    if (MODE == 3) {
        __syncthreads();
        u16* cb = (u16*)C + (size_t)(m0 >> 7) * (768 * 128) + (m0 & 127);
#pragma unroll
        for (int u = 0; u < 4; u++) {
            const int i = tid + u * 256;
            const int hl = i >> 4;
            const int s4 = (i & 15) << 2;
            ushort4 o;
            o.x = Ts[hl][s4 + 0]; o.y = Ts[hl][s4 + 1];
            o.z = Ts[hl][s4 + 2]; o.w = Ts[hl][s4 + 3];
            *(ushort4*)(cb + (size_t)(n0 + hl) * 128 + s4) = o;
        }
    }
}

// ---------------------------------------------------------------------------
// K0: weight transpose+convert only. grid 8064.
// ---------------------------------------------------------------------------
__global__ __launch_bounds__(256) void prep_kernel(
    const float* __restrict__ W1, const float* __restrict__ Wf1,
    const float* __restrict__ Wf2,
    u16* __restrict__ w1t, u16* __restrict__ wf1t, u16* __restrict__ wf2t)
{
    const int tid = threadIdx.x;
    int bid = blockIdx.x;
    const float* in; u16* outp; int tx, ty;
    if (bid < 4608) {
        const int z = bid / 1152, r = bid % 1152;
        tx = r % 24; ty = r / 24;
        in = W1 + (size_t)z * 1536 * 768; outp = w1t + (size_t)z * 768 * 1536;
    } else if (bid < 6912) {
        const int r = bid - 4608;
        tx = r % 48; ty = r / 48;
        in = Wf1; outp = wf1t;
    } else {
        const int r = bid - 6912;
        tx = r % 24; ty = r / 24;
        in = Wf2; outp = wf2t;
    }
    const int C = (bid >= 4608 && bid < 6912) ? 1536 : 768;
    const int c0 = tx * 32, r0 = ty * 32;
    __shared__ float tile[32][33];
    const int tr = tid >> 3, tc = (tid & 7) << 2;
    float4 v = *(const float4*)(in + (size_t)(r0 + tr) * C + c0 + tc);
    tile[tr][tc] = v.x; tile[tr][tc + 1] = v.y;
    tile[tr][tc + 2] = v.z; tile[tr][tc + 3] = v.w;
    __syncthreads();
    ushort4 o;
    o.x = f2bf(tile[tc + 0][tr]); o.y = f2bf(tile[tc + 1][tr]);
    o.z = f2bf(tile[tc + 2][tr]); o.w = f2bf(tile[tc + 3][tr]);
    *(ushort4*)(outp + (size_t)(c0 + tr) * 1536 + r0 + tc) = o;
}

// K1: 8 GEMMs (f32 A direct) -> sx (b1 folded, f16 rows), py_t (f16 transposed).
__global__ __launch_bounds__(256) void gemm_sxpy_kernel(
    const float* __restrict__ sp, const float* __restrict__ ph,
    const u16* __restrict__ w1t, const float* __restrict__ b1,
    u16* __restrict__ sxf, u16* __restrict__ pyt)
{
    const int z = blockIdx.z;
    const int n = z & 3;
    const bool ispy = z >= 4;
    const u16* Bt = w1t + (size_t)n * 768 * 1536 + (ispy ? 768 : 0);
    if (!ispy) {
        gemm_mfma_body<false, 2, true, false>(sp, nullptr, 768, Bt, 1536, b1 + n * HD_,
                                              sxf + (size_t)n * M_ * HD_, HD_, 768,
                                              blockIdx.y * 64, blockIdx.x * 64);
    } else {
        gemm_mfma_body<false, 3, true, false>(ph, nullptr, 768, Bt, 1536, nullptr,
                                              pyt + (size_t)n * 4 * 768 * 128, 0, 768,
                                              blockIdx.y * 64, blockIdx.x * 64);
    }
}

// K4: FFN1 split-A: hbuf = relu([speech|ctx] @ Wf1 + bf1), bf16 out. grid (24,8)
__global__ __launch_bounds__(256) void gemm_ffn1_kernel(
    const float* __restrict__ speech, const float* __restrict__ ctx,
    const u16* __restrict__ wf1t, const float* __restrict__ bf1,
    u16* __restrict__ hbuf)
{
    gemm_mfma_body<true, 1, true, true>(speech, ctx, 768, wf1t, 1536, bf1,
                                        hbuf, 1536, 1536,
                                        blockIdx.y * 64, blockIdx.x * 64);
}

// K5: FFN2: outpre = hbuf @ Wf2 + bf2, f32 out. grid (12,8)
__global__ __launch_bounds__(256) void gemm_ffn2_kernel(
    const u16* __restrict__ hbuf, const u16* __restrict__ wf2t,
    const float* __restrict__ bf2, float* __restrict__ outpre)
{
    gemm_mfma_body<false, 0, false, false>(hbuf, nullptr, 1536, wf2t, 1536, bf2,
                                           outpre, 768, 1536,
                                           blockIdx.y * 64, blockIdx.x * 64);
}

// ---------------------------------------------------------------------------
// K2: scores + softmax — PROVEN round-2 geometry (21us): block=(n,b,t8),
// 4 waves lockstep on ONE py panel (L1 sharing), wave = 2 t-rows.
// ---------------------------------------------------------------------------
__global__ __launch_bounds__(256) void scores_softmax_kernel(
    const u16* __restrict__ sxf,     // f16 [n][512][768]
    const u16* __restrict__ pyt,     // f16 [n][b][768][128]
    const float* __restrict__ w2,    // f32 [n][768]
    float* __restrict__ probs)       // f32 [n][512][128], 0.25-scaled
{
    const int bid = blockIdx.x;
    const int n = bid >> 6, b = (bid >> 4) & 3, t0 = (bid & 15) * 8;
    const int tid = threadIdx.x, lane = tid & 63, w = tid >> 6;

    __shared__ __align__(16) f16x2 sxs[8][768];
    __shared__ __align__(16) f16x2 w2s[768];

    for (int q = 0; q < 6; q++) {
        const int u = tid + q * 256;
        const int r = u / 192;
        const int h4 = (u % 192) * 4;
        ushort4 v = *(const ushort4*)(sxf + ((size_t)(n * 512 + b * 128 + t0 + r)) * 768 + h4);
        sxs[r][h4 + 0] = bcast2(splat2(v.x));
        sxs[r][h4 + 1] = bcast2(splat2(v.y));
        sxs[r][h4 + 2] = bcast2(splat2(v.z));
        sxs[r][h4 + 3] = bcast2(splat2(v.w));
    }
    for (int q = 0; q < 3; q++) {
        const int i = tid + q * 256;
        w2s[i] = bcast2(splat2(f16bits((f16)w2[n * 768 + i])));
    }
    __syncthreads();

    const f16x2* pypanel = (const f16x2*)(pyt + ((size_t)((n << 2) | b)) * 768 * 128) + lane;
    const f16x2 z2 = {(f16)0, (f16)0};

    float accA0 = 0.f, accA1 = 0.f, accB0 = 0.f, accB1 = 0.f;
    const int rA = 2 * w, rB = 2 * w + 1;

    f16x2 b0[16], b1[16];
#pragma unroll
    for (int j = 0; j < 16; j++) b0[j] = pypanel[(size_t)j * 64];
#pragma unroll
    for (int j = 0; j < 16; j++) b1[j] = pypanel[(size_t)(16 + j) * 64];

    auto compute = [&](const f16x2 (&buf)[16], int hbase) {
        f16x2 aA = z2, aB = z2;
#pragma unroll
        for (int j4 = 0; j4 < 16; j4 += 4) {
            uint4 sau = *(const uint4*)&sxs[rA][hbase + j4];
            uint4 sbu = *(const uint4*)&sxs[rB][hbase + j4];
            uint4 wvu = *(const uint4*)&w2s[hbase + j4];
            const u32 sa_[4] = {sau.x, sau.y, sau.z, sau.w};
            const u32 sb_[4] = {sbu.x, sbu.y, sbu.z, sbu.w};
            const u32 wv_[4] = {wvu.x, wvu.y, wvu.z, wvu.w};
#pragma unroll
            for (int j = 0; j < 4; j++) {
                const f16x2 pv = buf[j4 + j];
                const f16x2 wj = bcast2(wv_[j]);
                f16x2 ra = __builtin_elementwise_max(bcast2(sa_[j]) + pv, z2);
                f16x2 rb = __builtin_elementwise_max(bcast2(sb_[j]) + pv, z2);
                aA = __builtin_elementwise_fma(ra, wj, aA);
                aB = __builtin_elementwise_fma(rb, wj, aB);
            }
        }
        accA0 += (float)aA.x; accA1 += (float)aA.y;
        accB0 += (float)aB.x; accB1 += (float)aB.y;
    };

    for (int hc = 0; hc < 768; hc += 32) {
        compute(b0, hc);
        if (hc + 32 < 768) {
#pragma unroll
            for (int j = 0; j < 16; j++) b0[j] = pypanel[(size_t)(hc + 32 + j) * 64];
        }
        compute(b1, hc + 16);
        if (hc + 48 < 768) {
#pragma unroll
            for (int j = 0; j < 16; j++) b1[j] = pypanel[(size_t)(hc + 48 + j) * 64];
        }
    }

#pragma unroll
    for (int which = 0; which < 2; which++) {
        const float s0 = which ? accB0 : accA0;
        const float s1 = which ? accB1 : accA1;
        const int t = t0 + 2 * w + which;
        float mx = fmaxf(s0, s1);
#pragma unroll
        for (int off = 32; off; off >>= 1) mx = fmaxf(mx, __shfl_xor(mx, off, 64));
        const float e0 = expf(s0 - mx), e1 = expf(s1 - mx);
        float sm = e0 + e1;
#pragma unroll
        for (int off = 32; off; off >>= 1) sm += __shfl_xor(sm, off, 64);
        const float inv = 0.25f / sm;
        float2 pr; pr.x = e0 * inv; pr.y = e1 * inv;
        *(float2*)&probs[((size_t)(n * 512 + b * 128 + t)) * 128 + 2 * lane] = pr;
    }
}

// K3: ctx[m] = (sum_n probs[n,m]) @ phon[b], f32 out. grid 512.
__global__ __launch_bounds__(256) void context_kernel(
    const float* __restrict__ probs, const float* __restrict__ phon,
    float* __restrict__ ctx)
{
    const int m = blockIdx.x;
    const int b = m >> 7;
    const int tid = threadIdx.x;
    __shared__ float attn[T2_];
    if (tid < T2_) {
        float a = 0.f;
#pragma unroll
        for (int n = 0; n < NH_; n++)
            a += probs[(size_t)(n * M_ + m) * T2_ + tid];
        attn[tid] = a;
    }
    __syncthreads();
    const float* ph = phon + (size_t)b * T2_ * D_;
#pragma unroll
    for (int j = 0; j < 3; j++) {
        const int d = tid + 256 * j;
        float acc = 0.f;
#pragma unroll 8
        for (int s = 0; s < T2_; s++)
            acc = fmaf(attn[s], ph[(size_t)s * D_ + d], acc);
        ctx[(size_t)m * D_ + d] = acc;
    }
}

// K6: fused LN stats + time-mean. grid 12 = (b, 256-d chunk); stats redundant x3.
__global__ __launch_bounds__(256) void ln_fused_kernel(
    const float* __restrict__ x, const float* __restrict__ g,
    const float* __restrict__ lb, float* __restrict__ out)
{
    const int b = blockIdx.x / 3, c = blockIdx.x % 3;
    const int tid = threadIdx.x, lane = tid & 63, w = tid >> 6;
    __shared__ float rs[T1_];
    __shared__ float Sred[4];

    float prsum = 0.f;
    for (int i = 0; i < 32; i++) {
        const int row = w * 32 + i;
        const float4* x4 = (const float4*)(x + ((size_t)(b * T1_ + row)) * D_);
        float s = 0.f, ss = 0.f;
#pragma unroll
        for (int j = 0; j < 3; j++) {
            float4 v = x4[j * 64 + lane];
            s += v.x + v.y + v.z + v.w;
            ss += v.x * v.x + v.y * v.y + v.z * v.z + v.w * v.w;
        }
#pragma unroll
        for (int off = 32; off; off >>= 1) {
            s += __shfl_xor(s, off, 64);
            ss += __shfl_xor(ss, off, 64);
        }
        if (lane == 0) {
            const float mu = s * (1.f / D_);
            const float var = ss * (1.f / D_) - mu * mu;
            const float r = rsqrtf(var + LN_EPS_);
            rs[row] = r;
            prsum += mu * r;
        }
    }
    if (lane == 0) Sred[w] = prsum;
    __syncthreads();
    const float S = Sred[0] + Sred[1] + Sred[2] + Sred[3];
    const float* xb = x + (size_t)b * T1_ * D_;
    const int d = c * 256 + tid;
    float acc = 0.f;
#pragma unroll 8
    for (int t = 0; t < T1_; t++)
        acc = fmaf(xb[(size_t)t * D_ + d], rs[t], acc);
    out[b * D_ + d] = g[d] * (acc - S) * (1.f / T1_) + lb[d];
}

extern "C" void kernel_launch(void* const* d_in, const int* in_sizes, int n_in,
                              void* d_out, int out_size, void* d_ws, size_t ws_size,
                              hipStream_t stream)
{
    const float* speech = (const float*)d_in[0];
    const float* phon   = (const float*)d_in[1];
    const float* W1     = (const float*)d_in[2];
    const float* b1     = (const float*)d_in[3];
    const float* w2     = (const float*)d_in[4];
    // d_in[5] = b2: softmax-invariant, unused
    const float* Wf1    = (const float*)d_in[6];
    const float* bf1    = (const float*)d_in[7];
    const float* Wf2    = (const float*)d_in[8];
    const float* bf2    = (const float*)d_in[9];
    const float* ln_g   = (const float*)d_in[10];
    const float* ln_b   = (const float*)d_in[11];
    float* out = (float*)d_out;

    char* w = (char*)d_ws;
    auto alloc = [&](size_t bytes) { char* p = w; w += (bytes + 1023) & ~(size_t)1023; return p; };
    u16* w1t    = (u16*)alloc((size_t)NH_ * 768 * 1536 * 2);
    u16* wf1t   = (u16*)alloc((size_t)1536 * 1536 * 2);
    u16* wf2t   = (u16*)alloc((size_t)768 * 1536 * 2);
    u16* sxf    = (u16*)alloc((size_t)NH_ * M_ * HD_ * 2);        // f16
    u16* pyt    = (u16*)alloc((size_t)NH_ * B_ * 768 * 128 * 2);  // f16 transposed
    float* probs  = (float*)alloc((size_t)NH_ * M_ * T2_ * 4);
    float* ctxb   = (float*)alloc((size_t)M_ * D_ * 4);
    u16* hbuf   = (u16*)alloc((size_t)M_ * 2 * HD_ * 2);
    float* outpre = (float*)alloc((size_t)M_ * D_ * 4);

    hipLaunchKernelGGL(prep_kernel, dim3(8064), dim3(256), 0, stream,
                       W1, Wf1, Wf2, w1t, wf1t, wf2t);
    hipLaunchKernelGGL(gemm_sxpy_kernel, dim3(HD_ / 64, M_ / 64, 8), dim3(256), 0, stream,
                       speech, phon, w1t, b1, sxf, pyt);
    hipLaunchKernelGGL(scores_softmax_kernel, dim3(256), dim3(256), 0, stream,
                       sxf, pyt, w2, probs);
    hipLaunchKernelGGL(context_kernel, dim3(M_), dim3(256), 0, stream,
                       probs, phon, ctxb);
    hipLaunchKernelGGL(gemm_ffn1_kernel, dim3(2 * HD_ / 64, M_ / 64), dim3(256), 0, stream,
                       speech, ctxb, wf1t, bf1, hbuf);
    hipLaunchKernelGGL(gemm_ffn2_kernel, dim3(D_ / 64, M_ / 64), dim3(256), 0, stream,
                       hbuf, wf2t, bf2, outpre);
    hipLaunchKernelGGL(ln_fused_kernel, dim3(12), dim3(256), 0, stream,
                       outpre, ln_g, ln_b, out);
}

// Round 15
// 129.456 us; speedup vs baseline: 1.1017x; 1.1017x over previous
//
#include <hip/hip_runtime.h>
#include <cstddef>

// ----------------------------------------------------------------------------
// AttentionFusion round 14b: 6 launches, context kernel eliminated by
// associativity: ctx@Wf1_bot = attn@(phon@Wf1_bot) = attn@PW.
//  K0 prep: weight transpose (w1t, wf1t, wf2t)
//  K1 sxpyPW: sx (f16 rows) + py_t (f16 transposed) + PW_t (bf16 transposed)
//  K2 scores: PROVEN r2 geometry (4 waves lockstep on one panel, 21us)
//  K3 FFN1': K=896, A=[speech | sum_n probs] staged on the fly
//  K4 FFN2, K5 ln_fused
// (r14 failed on a dead leftover kernel; removed.)
// ----------------------------------------------------------------------------

#define D_  768
#define HD_ 768
#define NH_ 4
#define B_  4
#define T1_ 128
#define T2_ 128
#define M_  (B_*T1_)
#define LN_EPS_ 1e-5f

typedef unsigned short u16;
typedef unsigned int u32;
typedef _Float16 f16;
typedef _Float16 f16x2 __attribute__((ext_vector_type(2)));
typedef __bf16 bf16x8 __attribute__((ext_vector_type(8)));
typedef float f32x4 __attribute__((ext_vector_type(4)));

__device__ __forceinline__ u16 f2bf(float f) {
    union { float f; unsigned int u; } v; v.f = f;
    unsigned int u = v.u + (0x7FFFu + ((v.u >> 16) & 1u));
    return (u16)(u >> 16);
}
__device__ __forceinline__ u32 pack_bf2(float lo, float hi) {
    return (u32)f2bf(lo) | ((u32)f2bf(hi) << 16);
}
__device__ __forceinline__ u16 f16bits(f16 h) {
    return __builtin_bit_cast(unsigned short, h);
}
__device__ __forceinline__ f16x2 bcast2(u32 u) {
    return __builtin_bit_cast(f16x2, u);
}
__device__ __forceinline__ u32 splat2(u16 h) { return (u32)h * 0x10001u; }

// ---------------- bf16 MFMA GEMM: C = A @ Bt^T + bias ----------------------
// AF32: A is f32 (bf16-converted during staging).
// MODE: 0=f32 rows, 1=bf16 rows, 2=f16 rows, 3=f16 transposed, 4=bf16 transposed
template<bool RELU, int MODE, bool AF32>
__device__ __forceinline__ void gemm_mfma_body(
    const void* __restrict__ Av, int lda,
    const u16* __restrict__ Bt, int ldb,
    const float* __restrict__ bias,
    void* __restrict__ C, int ldc, int K, int m0, int n0)
{
    __shared__ __align__(16) u16 As[64][40];
    __shared__ __align__(16) u16 Bs[64][40];
    __shared__ u16 Ts[MODE >= 3 ? 64 : 1][MODE >= 3 ? 68 : 1];

    const int tid = threadIdx.x;
    const int row = tid >> 2;
    const int kq  = (tid & 3) << 3;
    const int lane = tid & 63;
    const int w  = tid >> 6;
    const int wr = (w >> 1) << 5;
    const int wc = (w & 1) << 5;
    const int l16 = lane & 15;
    const int lk8 = (lane >> 4) << 3;
    const int r4  = (lane >> 4) << 2;

    const u16*   aptr16 = (const u16*)Av + (size_t)(m0 + row) * lda + kq;
    const float* aptrf  = (const float*)Av + (size_t)(m0 + row) * lda + kq;
    const u16*   bptr   = Bt + (size_t)(n0 + row) * ldb + kq;

    f32x4 acc00 = {0.f,0.f,0.f,0.f}, acc01 = {0.f,0.f,0.f,0.f};
    f32x4 acc10 = {0.f,0.f,0.f,0.f}, acc11 = {0.f,0.f,0.f,0.f};

    auto loadA = [&](int k0) -> uint4 {
        if (AF32) {
            float4 ax = *(const float4*)(aptrf + k0);
            float4 ay = *(const float4*)(aptrf + k0 + 4);
            uint4 r;
            r.x = pack_bf2(ax.x, ax.y); r.y = pack_bf2(ax.z, ax.w);
            r.z = pack_bf2(ay.x, ay.y); r.w = pack_bf2(ay.z, ay.w);
            return r;
        }
        return *(const uint4*)(aptr16 + k0);
    };

    uint4 a_nxt = loadA(0);
    uint4 b_nxt = *(const uint4*)bptr;

    for (int k0 = 0; k0 < K; k0 += 32) {
        __syncthreads();
        *(uint4*)&As[row][kq] = a_nxt;
        *(uint4*)&Bs[row][kq] = b_nxt;
        if (k0 + 32 < K) {
            a_nxt = loadA(k0 + 32);
            b_nxt = *(const uint4*)(bptr + k0 + 32);
        }
        __syncthreads();
        bf16x8 af0 = *(const bf16x8*)&As[wr + l16][lk8];
        bf16x8 af1 = *(const bf16x8*)&As[wr + 16 + l16][lk8];
        bf16x8 bf0 = *(const bf16x8*)&Bs[wc + l16][lk8];
        bf16x8 bf1 = *(const bf16x8*)&Bs[wc + 16 + l16][lk8];
        acc00 = __builtin_amdgcn_mfma_f32_16x16x32_bf16(af0, bf0, acc00, 0, 0, 0);
        acc01 = __builtin_amdgcn_mfma_f32_16x16x32_bf16(af0, bf1, acc01, 0, 0, 0);
        acc10 = __builtin_amdgcn_mfma_f32_16x16x32_bf16(af1, bf0, acc10, 0, 0, 0);
        acc11 = __builtin_amdgcn_mfma_f32_16x16x32_bf16(af1, bf1, acc11, 0, 0, 0);
    }

#define EPI_FRAG(ACC, MF, NF)                                                  \
    {                                                                          \
        const int gcol = n0 + wc + (NF)*16 + l16;                              \
        const float bv = bias ? bias[gcol] : 0.f;                              \
        float v_[4];                                                           \
        _Pragma("unroll")                                                      \
        for (int r = 0; r < 4; r++) {                                          \
            float v = ACC[r] + bv;                                             \
            if (RELU) v = fmaxf(v, 0.f);                                       \
            v_[r] = v;                                                         \
        }                                                                      \
        const int lr0 = wr + (MF)*16 + r4;                                     \
        if (MODE >= 3) {                                                       \
            const int lc = wc + (NF)*16 + l16;                                 \
            _Pragma("unroll")                                                  \
            for (int r = 0; r < 4; r++)                                        \
                Ts[lc][lr0 + r] = (MODE == 3) ? f16bits((f16)v_[r])            \
                                              : f2bf(v_[r]);                   \
        } else {                                                               \
            _Pragma("unroll")                                                  \
            for (int r = 0; r < 4; r++) {                                      \
                const size_t off = (size_t)(m0 + lr0 + r) * ldc + gcol;        \
                if (MODE == 0) ((float*)C)[off] = v_[r];                       \
                else if (MODE == 1) ((u16*)C)[off] = f2bf(v_[r]);              \
                else ((u16*)C)[off] = f16bits((f16)v_[r]);                     \
            }                                                                  \
        }                                                                      \
    }
    EPI_FRAG(acc00, 0, 0) EPI_FRAG(acc01, 0, 1)
    EPI_FRAG(acc10, 1, 0) EPI_FRAG(acc11, 1, 1)
#undef EPI_FRAG

    if (MODE >= 3) {
        // coalesced write of the 64(m->s) x 64(n->h) tile into C[h][128]
        __syncthreads();
        u16* cb = (u16*)C + (size_t)(m0 >> 7) * ((size_t)ldc * 128) + (m0 & 127);
#pragma unroll
        for (int u = 0; u < 4; u++) {
            const int i = tid + u * 256;
            const int hl = i >> 4;
            const int s4 = (i & 15) << 2;
            ushort4 o;
            o.x = Ts[hl][s4 + 0]; o.y = Ts[hl][s4 + 1];
            o.z = Ts[hl][s4 + 2]; o.w = Ts[hl][s4 + 3];
            *(ushort4*)(cb + (size_t)(n0 + hl) * 128 + s4) = o;
        }
    }
}

// ---------------------------------------------------------------------------
// K0: weight transpose+convert. grid 8064.
// ---------------------------------------------------------------------------
__global__ __launch_bounds__(256) void prep_kernel(
    const float* __restrict__ W1, const float* __restrict__ Wf1,
    const float* __restrict__ Wf2,
    u16* __restrict__ w1t, u16* __restrict__ wf1t, u16* __restrict__ wf2t)
{
    const int tid = threadIdx.x;
    int bid = blockIdx.x;
    const float* in; u16* outp; int tx, ty;
    if (bid < 4608) {
        const int z = bid / 1152, r = bid % 1152;
        tx = r % 24; ty = r / 24;
        in = W1 + (size_t)z * 1536 * 768; outp = w1t + (size_t)z * 768 * 1536;
    } else if (bid < 6912) {
        const int r = bid - 4608;
        tx = r % 48; ty = r / 48;
        in = Wf1; outp = wf1t;
    } else {
        const int r = bid - 6912;
        tx = r % 24; ty = r / 24;
        in = Wf2; outp = wf2t;
    }
    const int C = (bid >= 4608 && bid < 6912) ? 1536 : 768;
    const int c0 = tx * 32, r0 = ty * 32;
    __shared__ float tile[32][33];
    const int tr = tid >> 3, tc = (tid & 7) << 2;
    float4 v = *(const float4*)(in + (size_t)(r0 + tr) * C + c0 + tc);
    tile[tr][tc] = v.x; tile[tr][tc + 1] = v.y;
    tile[tr][tc + 2] = v.z; tile[tr][tc + 3] = v.w;
    __syncthreads();
    ushort4 o;
    o.x = f2bf(tile[tc + 0][tr]); o.y = f2bf(tile[tc + 1][tr]);
    o.z = f2bf(tile[tc + 2][tr]); o.w = f2bf(tile[tc + 3][tr]);
    *(ushort4*)(outp + (size_t)(c0 + tr) * 1536 + r0 + tc) = o;
}

// ---------------------------------------------------------------------------
// K1: sx + py_t + PW_t batched. 1D grid 960.
//  job [0,384): sx head n      -> f16 rows [n][512][768]     (b1 folded)
//  job [384,768): py head n    -> f16 transposed [n][b][768][128]
//  job [768,960): PW batch b   -> bf16 transposed [b][1536][128]
// ---------------------------------------------------------------------------
__global__ __launch_bounds__(256) void sxpypw_kernel(
    const float* __restrict__ sp, const float* __restrict__ ph,
    const u16* __restrict__ w1t, const u16* __restrict__ wf1t,
    const float* __restrict__ b1,
    u16* __restrict__ sxf, u16* __restrict__ pyt, u16* __restrict__ pwt)
{
    int job = blockIdx.x;
    if (job < 384) {
        const int n = job / 96, r = job % 96, my = r / 12, nx = r % 12;
        gemm_mfma_body<false, 2, true>(sp, 768,
            w1t + (size_t)n * 768 * 1536, 1536, b1 + n * HD_,
            sxf + (size_t)n * M_ * HD_, HD_, 768, my * 64, nx * 64);
    } else if (job < 768) {
        const int j = job - 384;
        const int n = j / 96, r = j % 96, my = r / 12, nx = r % 12;
        gemm_mfma_body<false, 3, true>(ph, 768,
            w1t + (size_t)n * 768 * 1536 + 768, 1536, nullptr,
            pyt + (size_t)n * 4 * 768 * 128, 768, 768, my * 64, nx * 64);
    } else {
        const int j = job - 768;
        const int b = j / 48, r = j % 48, my = r / 24, nx = r % 24;
        // PW[b] = phon[b] @ Wf1_bot : A = phon[b] (128x768 f32),
        // Bt = wf1t rows with column offset 768 (row stride 1536),
        // out bf16 transposed [b][1536][128].
        gemm_mfma_body<false, 4, true>(ph + (size_t)b * 128 * 768, 768,
            wf1t + 768, 1536, nullptr,
            pwt + (size_t)b * 1536 * 128, 1536, 768, my * 64, nx * 64);
    }
}

// ---------------------------------------------------------------------------
// K2: scores + softmax — PROVEN r2 geometry: block=(n,b,t8), 4 waves lockstep
// on ONE py panel (L1 sharing), each wave 2 t-rows. Writes 0.25-scaled probs.
// ---------------------------------------------------------------------------
__global__ __launch_bounds__(256) void scores_softmax_kernel(
    const u16* __restrict__ sxf,     // f16 [n][512][768]
    const u16* __restrict__ pyt,     // f16 [n][b][768][128]
    const float* __restrict__ w2,    // f32 [n][768]
    float* __restrict__ probs)       // f32 [n][512][128]
{
    const int bid = blockIdx.x;
    const int n = bid >> 6, b = (bid >> 4) & 3, t0 = (bid & 15) * 8;
    const int tid = threadIdx.x, lane = tid & 63, w = tid >> 6;

    __shared__ __align__(16) f16x2 sxs[8][768];
    __shared__ __align__(16) f16x2 w2s[768];

    for (int q = 0; q < 6; q++) {
        const int u = tid + q * 256;
        const int r = u / 192;
        const int h4 = (u % 192) * 4;
        ushort4 v = *(const ushort4*)(sxf + ((size_t)(n * 512 + b * 128 + t0 + r)) * 768 + h4);
        sxs[r][h4 + 0] = bcast2(splat2(v.x));
        sxs[r][h4 + 1] = bcast2(splat2(v.y));
        sxs[r][h4 + 2] = bcast2(splat2(v.z));
        sxs[r][h4 + 3] = bcast2(splat2(v.w));
    }
    for (int q = 0; q < 3; q++) {
        const int i = tid + q * 256;
        w2s[i] = bcast2(splat2(f16bits((f16)w2[n * 768 + i])));
    }
    __syncthreads();

    const f16x2* pypanel = (const f16x2*)(pyt + ((size_t)((n << 2) | b)) * 768 * 128) + lane;
    const f16x2 z2 = {(f16)0, (f16)0};

    float accA0 = 0.f, accA1 = 0.f, accB0 = 0.f, accB1 = 0.f;
    const int rA = 2 * w, rB = 2 * w + 1;

    f16x2 b0[16], b1[16];
#pragma unroll
    for (int j = 0; j < 16; j++) b0[j] = pypanel[(size_t)j * 64];
#pragma unroll
    for (int j = 0; j < 16; j++) b1[j] = pypanel[(size_t)(16 + j) * 64];

    auto compute = [&](const f16x2 (&buf)[16], int hbase) {
        f16x2 aA = z2, aB = z2;
#pragma unroll
        for (int j4 = 0; j4 < 16; j4 += 4) {
            uint4 sau = *(const uint4*)&sxs[rA][hbase + j4];
            uint4 sbu = *(const uint4*)&sxs[rB][hbase + j4];
            uint4 wvu = *(const uint4*)&w2s[hbase + j4];
            const u32 sa_[4] = {sau.x, sau.y, sau.z, sau.w};
            const u32 sb_[4] = {sbu.x, sbu.y, sbu.z, sbu.w};
            const u32 wv_[4] = {wvu.x, wvu.y, wvu.z, wvu.w};
#pragma unroll
            for (int j = 0; j < 4; j++) {
                const f16x2 pv = buf[j4 + j];
                const f16x2 wj = bcast2(wv_[j]);
                f16x2 ra = __builtin_elementwise_max(bcast2(sa_[j]) + pv, z2);
                f16x2 rb = __builtin_elementwise_max(bcast2(sb_[j]) + pv, z2);
                aA = __builtin_elementwise_fma(ra, wj, aA);
                aB = __builtin_elementwise_fma(rb, wj, aB);
            }
        }
        accA0 += (float)aA.x; accA1 += (float)aA.y;
        accB0 += (float)aB.x; accB1 += (float)aB.y;
    };

    for (int hc = 0; hc < 768; hc += 32) {
        compute(b0, hc);
        if (hc + 32 < 768) {
#pragma unroll
            for (int j = 0; j < 16; j++) b0[j] = pypanel[(size_t)(hc + 32 + j) * 64];
        }
        compute(b1, hc + 16);
        if (hc + 48 < 768) {
#pragma unroll
            for (int j = 0; j < 16; j++) b1[j] = pypanel[(size_t)(hc + 48 + j) * 64];
        }
    }

#pragma unroll
    for (int which = 0; which < 2; which++) {
        const float s0 = which ? accB0 : accA0;
        const float s1 = which ? accB1 : accA1;
        const int t = t0 + 2 * w + which;
        float mx = fmaxf(s0, s1);
#pragma unroll
        for (int off = 32; off; off >>= 1) mx = fmaxf(mx, __shfl_xor(mx, off, 64));
        const float e0 = expf(s0 - mx), e1 = expf(s1 - mx);
        float sm = e0 + e1;
#pragma unroll
        for (int off = 32; off; off >>= 1) sm += __shfl_xor(sm, off, 64);
        const float inv = 0.25f / sm;
        float2 pr; pr.x = e0 * inv; pr.y = e1 * inv;
        *(float2*)&probs[((size_t)(n * 512 + b * 128 + t)) * 128 + 2 * lane] = pr;
    }
}

// ---------------------------------------------------------------------------
// K3: FFN1' : hbuf = relu(speech @ Wf1_top + attn @ PW[b] + bf1), K=896.
// attn rows (k>=768) are summed from the 4 heads' probs during staging.
// grid (24, 8).
// ---------------------------------------------------------------------------
__global__ __launch_bounds__(256) void gemm_ffn1_kernel(
    const float* __restrict__ speech, const float* __restrict__ probs,
    const u16* __restrict__ wf1t, const u16* __restrict__ pwt,
    const float* __restrict__ bf1, u16* __restrict__ hbuf)
{
    __shared__ __align__(16) u16 As[64][40];
    __shared__ __align__(16) u16 Bs[64][40];

    const int tid = threadIdx.x;
    const int row = tid >> 2;
    const int kq  = (tid & 3) << 3;
    const int lane = tid & 63;
    const int w  = tid >> 6;
    const int wr = (w >> 1) << 5;
    const int wc = (w & 1) << 5;
    const int l16 = lane & 15;
    const int lk8 = (lane >> 4) << 3;
    const int r4  = (lane >> 4) << 2;

    const int m0 = blockIdx.y * 64, n0 = blockIdx.x * 64;
    const int b = m0 >> 7;

    const float* arow = speech + (size_t)(m0 + row) * 768 + kq;
    const float* prow = probs + (size_t)(m0 + row) * 128 + kq;
    const u16* brow_w = wf1t + (size_t)(n0 + row) * 1536 + kq;
    const u16* brow_p = pwt + (size_t)b * 1536 * 128 + (size_t)(n0 + row) * 128 + kq;

    f32x4 acc00 = {0.f,0.f,0.f,0.f}, acc01 = {0.f,0.f,0.f,0.f};
    f32x4 acc10 = {0.f,0.f,0.f,0.f}, acc11 = {0.f,0.f,0.f,0.f};

    auto loadA = [&](int k0) -> uint4 {
        uint4 r;
        if (k0 < 768) {
            float4 ax = *(const float4*)(arow + k0);
            float4 ay = *(const float4*)(arow + k0 + 4);
            r.x = pack_bf2(ax.x, ax.y); r.y = pack_bf2(ax.z, ax.w);
            r.z = pack_bf2(ay.x, ay.y); r.w = pack_bf2(ay.z, ay.w);
        } else {
            const int ko = k0 - 768;
            float4 ax = make_float4(0.f, 0.f, 0.f, 0.f), ay = ax;
#pragma unroll
            for (int n = 0; n < 4; n++) {
                float4 u0 = *(const float4*)(prow + (size_t)n * 512 * 128 + ko);
                float4 u1 = *(const float4*)(prow + (size_t)n * 512 * 128 + ko + 4);
                ax.x += u0.x; ax.y += u0.y; ax.z += u0.z; ax.w += u0.w;
                ay.x += u1.x; ay.y += u1.y; ay.z += u1.z; ay.w += u1.w;
            }
            r.x = pack_bf2(ax.x, ax.y); r.y = pack_bf2(ax.z, ax.w);
            r.z = pack_bf2(ay.x, ay.y); r.w = pack_bf2(ay.z, ay.w);
        }
        return r;
    };
    auto loadB = [&](int k0) -> uint4 {
        if (k0 < 768) return *(const uint4*)(brow_w + k0);
        return *(const uint4*)(brow_p + (k0 - 768));
    };

    uint4 a_nxt = loadA(0);
    uint4 b_nxt = loadB(0);

    for (int k0 = 0; k0 < 896; k0 += 32) {
        __syncthreads();
        *(uint4*)&As[row][kq] = a_nxt;
        *(uint4*)&Bs[row][kq] = b_nxt;
        if (k0 + 32 < 896) {
            a_nxt = loadA(k0 + 32);
            b_nxt = loadB(k0 + 32);
        }
        __syncthreads();
        bf16x8 af0 = *(const bf16x8*)&As[wr + l16][lk8];
        bf16x8 af1 = *(const bf16x8*)&As[wr + 16 + l16][lk8];
        bf16x8 bf0 = *(const bf16x8*)&Bs[wc + l16][lk8];
        bf16x8 bf1 = *(const bf16x8*)&Bs[wc + 16 + l16][lk8];
        acc00 = __builtin_amdgcn_mfma_f32_16x16x32_bf16(af0, bf0, acc00, 0, 0, 0);
        acc01 = __builtin_amdgcn_mfma_f32_16x16x32_bf16(af0, bf1, acc01, 0, 0, 0);
        acc10 = __builtin_amdgcn_mfma_f32_16x16x32_bf16(af1, bf0, acc10, 0, 0, 0);
        acc11 = __builtin_amdgcn_mfma_f32_16x16x32_bf16(af1, bf1, acc11, 0, 0, 0);
    }

#define EPI_FFN1(ACC, MF, NF)                                                  \
    {                                                                          \
        const int gcol = n0 + wc + (NF)*16 + l16;                              \
        const float bv = bf1[gcol];                                            \
        const int lr0 = wr + (MF)*16 + r4;                                     \
        _Pragma("unroll")                                                      \
        for (int r = 0; r < 4; r++) {                                          \
            float v = fmaxf(ACC[r] + bv, 0.f);                                 \
            hbuf[(size_t)(m0 + lr0 + r) * 1536 + gcol] = f2bf(v);              \
        }                                                                      \
    }
    EPI_FFN1(acc00, 0, 0) EPI_FFN1(acc01, 0, 1)
    EPI_FFN1(acc10, 1, 0) EPI_FFN1(acc11, 1, 1)
#undef EPI_FFN1
}

// K4: FFN2: outpre = hbuf @ Wf2 + bf2, f32 out. grid (12,8)
__global__ __launch_bounds__(256) void gemm_ffn2_kernel(
    const u16* __restrict__ hbuf, const u16* __restrict__ wf2t,
    const float* __restrict__ bf2, float* __restrict__ outpre)
{
    gemm_mfma_body<false, 0, false>(hbuf, 1536, wf2t, 1536, bf2,
                                    outpre, 768, 1536,
                                    blockIdx.y * 64, blockIdx.x * 64);
}

// K5: fused LN stats + time-mean. grid 12 = (b, 256-d chunk).
__global__ __launch_bounds__(256) void ln_fused_kernel(
    const float* __restrict__ x, const float* __restrict__ g,
    const float* __restrict__ lb, float* __restrict__ out)
{
    const int b = blockIdx.x / 3, c = blockIdx.x % 3;
    const int tid = threadIdx.x, lane = tid & 63, w = tid >> 6;
    __shared__ float rs[T1_];
    __shared__ float Sred[4];

    float prsum = 0.f;
    for (int i = 0; i < 32; i++) {
        const int row = w * 32 + i;
        const float4* x4 = (const float4*)(x + ((size_t)(b * T1_ + row)) * D_);
        float s = 0.f, ss = 0.f;
#pragma unroll
        for (int j = 0; j < 3; j++) {
            float4 v = x4[j * 64 + lane];
            s += v.x + v.y + v.z + v.w;
            ss += v.x * v.x + v.y * v.y + v.z * v.z + v.w * v.w;
        }
#pragma unroll
        for (int off = 32; off; off >>= 1) {
            s += __shfl_xor(s, off, 64);
            ss += __shfl_xor(ss, off, 64);
        }
        if (lane == 0) {
            const float mu = s * (1.f / D_);
            const float var = ss * (1.f / D_) - mu * mu;
            const float r = rsqrtf(var + LN_EPS_);
            rs[row] = r;
            prsum += mu * r;
        }
    }
    if (lane == 0) Sred[w] = prsum;
    __syncthreads();
    const float S = Sred[0] + Sred[1] + Sred[2] + Sred[3];
    const float* xb = x + (size_t)b * T1_ * D_;
    const int d = c * 256 + tid;
    float acc = 0.f;
#pragma unroll 8
    for (int t = 0; t < T1_; t++)
        acc = fmaf(xb[(size_t)t * D_ + d], rs[t], acc);
    out[b * D_ + d] = g[d] * (acc - S) * (1.f / T1_) + lb[d];
}

extern "C" void kernel_launch(void* const* d_in, const int* in_sizes, int n_in,
                              void* d_out, int out_size, void* d_ws, size_t ws_size,
                              hipStream_t stream)
{
    const float* speech = (const float*)d_in[0];
    const float* phon   = (const float*)d_in[1];
    const float* W1     = (const float*)d_in[2];
    const float* b1     = (const float*)d_in[3];
    const float* w2     = (const float*)d_in[4];
    // d_in[5] = b2: softmax-invariant, unused
    const float* Wf1    = (const float*)d_in[6];
    const float* bf1    = (const float*)d_in[7];
    const float* Wf2    = (const float*)d_in[8];
    const float* bf2    = (const float*)d_in[9];
    const float* ln_g   = (const float*)d_in[10];
    const float* ln_b   = (const float*)d_in[11];
    float* out = (float*)d_out;

    char* w = (char*)d_ws;
    auto alloc = [&](size_t bytes) { char* p = w; w += (bytes + 1023) & ~(size_t)1023; return p; };
    u16* w1t    = (u16*)alloc((size_t)NH_ * 768 * 1536 * 2);
    u16* wf1t   = (u16*)alloc((size_t)1536 * 1536 * 2);
    u16* wf2t   = (u16*)alloc((size_t)768 * 1536 * 2);
    u16* sxf    = (u16*)alloc((size_t)NH_ * M_ * HD_ * 2);        // f16
    u16* pyt    = (u16*)alloc((size_t)NH_ * B_ * 768 * 128 * 2);  // f16 transposed
    u16* pwt    = (u16*)alloc((size_t)B_ * 1536 * 128 * 2);       // bf16 transposed
    float* probs  = (float*)alloc((size_t)NH_ * M_ * T2_ * 4);
    u16* hbuf   = (u16*)alloc((size_t)M_ * 2 * HD_ * 2);
    float* outpre = (float*)alloc((size_t)M_ * D_ * 4);

    hipLaunchKernelGGL(prep_kernel, dim3(8064), dim3(256), 0, stream,
                       W1, Wf1, Wf2, w1t, wf1t, wf2t);
    hipLaunchKernelGGL(sxpypw_kernel, dim3(960), dim3(256), 0, stream,
                       speech, phon, w1t, wf1t, b1, sxf, pyt, pwt);
    hipLaunchKernelGGL(scores_softmax_kernel, dim3(256), dim3(256), 0, stream,
                       sxf, pyt, w2, probs);
    hipLaunchKernelGGL(gemm_ffn1_kernel, dim3(24, 8), dim3(256), 0, stream,
                       speech, probs, wf1t, pwt, bf1, hbuf);
    hipLaunchKernelGGL(gemm_ffn2_kernel, dim3(12, 8), dim3(256), 0, stream,
                       hbuf, wf2t, bf2, outpre);
    hipLaunchKernelGGL(ln_fused_kernel, dim3(12), dim3(256), 0, stream,
                       outpre, ln_g, ln_b, out);
}

// Round 16
// 118.152 us; speedup vs baseline: 1.2071x; 1.0957x over previous
//
#include <hip/hip_runtime.h>
#include <cstddef>

// ----------------------------------------------------------------------------
// AttentionFusion round 16: r14b structure (6 launches, PW associativity),
// with the LDS-bloat fix: gemm_mfma_body takes an explicit smem pointer so a
// kernel instantiating multiple MODEs unions ONE 18.9KB buffer instead of
// summing 48KB of per-instantiation static __shared__ (measured: sxpypw
// LDS_Block_Size=48128 -> 1.7 blocks/CU -> MfmaUtil 5%, 42us).
// ----------------------------------------------------------------------------

#define D_  768
#define HD_ 768
#define NH_ 4
#define B_  4
#define T1_ 128
#define T2_ 128
#define M_  (B_*T1_)
#define LN_EPS_ 1e-5f
#define GEMM_SMEM 18944   // As 5120 + Bs 5120 + Ts 8704

typedef unsigned short u16;
typedef unsigned int u32;
typedef _Float16 f16;
typedef _Float16 f16x2 __attribute__((ext_vector_type(2)));
typedef __bf16 bf16x8 __attribute__((ext_vector_type(8)));
typedef float f32x4 __attribute__((ext_vector_type(4)));

__device__ __forceinline__ u16 f2bf(float f) {
    union { float f; unsigned int u; } v; v.f = f;
    unsigned int u = v.u + (0x7FFFu + ((v.u >> 16) & 1u));
    return (u16)(u >> 16);
}
__device__ __forceinline__ u32 pack_bf2(float lo, float hi) {
    return (u32)f2bf(lo) | ((u32)f2bf(hi) << 16);
}
__device__ __forceinline__ u16 f16bits(f16 h) {
    return __builtin_bit_cast(unsigned short, h);
}
__device__ __forceinline__ f16x2 bcast2(u32 u) {
    return __builtin_bit_cast(f16x2, u);
}
__device__ __forceinline__ u32 splat2(u16 h) { return (u32)h * 0x10001u; }

// ---------------- bf16 MFMA GEMM: C = A @ Bt^T + bias ----------------------
// AF32: A is f32 (bf16-converted during staging).
// MODE: 0=f32 rows, 1=bf16 rows, 2=f16 rows, 3=f16 transposed, 4=bf16 transposed
// smem: caller-provided buffer, >= GEMM_SMEM bytes, 16B-aligned.
template<bool RELU, int MODE, bool AF32>
__device__ __forceinline__ void gemm_mfma_body(
    const void* __restrict__ Av, int lda,
    const u16* __restrict__ Bt, int ldb,
    const float* __restrict__ bias,
    void* __restrict__ C, int ldc, int K, int m0, int n0, char* smem)
{
    u16 (*As)[40] = reinterpret_cast<u16(*)[40]>(smem);           // 5120 B
    u16 (*Bs)[40] = reinterpret_cast<u16(*)[40]>(smem + 5120);    // 5120 B
    u16 (*Ts)[68] = reinterpret_cast<u16(*)[68]>(smem + 10240);   // 8704 B

    const int tid = threadIdx.x;
    const int row = tid >> 2;
    const int kq  = (tid & 3) << 3;
    const int lane = tid & 63;
    const int w  = tid >> 6;
    const int wr = (w >> 1) << 5;
    const int wc = (w & 1) << 5;
    const int l16 = lane & 15;
    const int lk8 = (lane >> 4) << 3;
    const int r4  = (lane >> 4) << 2;

    const u16*   aptr16 = (const u16*)Av + (size_t)(m0 + row) * lda + kq;
    const float* aptrf  = (const float*)Av + (size_t)(m0 + row) * lda + kq;
    const u16*   bptr   = Bt + (size_t)(n0 + row) * ldb + kq;

    f32x4 acc00 = {0.f,0.f,0.f,0.f}, acc01 = {0.f,0.f,0.f,0.f};
    f32x4 acc10 = {0.f,0.f,0.f,0.f}, acc11 = {0.f,0.f,0.f,0.f};

    auto loadA = [&](int k0) -> uint4 {
        if (AF32) {
            float4 ax = *(const float4*)(aptrf + k0);
            float4 ay = *(const float4*)(aptrf + k0 + 4);
            uint4 r;
            r.x = pack_bf2(ax.x, ax.y); r.y = pack_bf2(ax.z, ax.w);
            r.z = pack_bf2(ay.x, ay.y); r.w = pack_bf2(ay.z, ay.w);
            return r;
        }
        return *(const uint4*)(aptr16 + k0);
    };

    uint4 a_nxt = loadA(0);
    uint4 b_nxt = *(const uint4*)bptr;

    for (int k0 = 0; k0 < K; k0 += 32) {
        __syncthreads();
        *(uint4*)&As[row][kq] = a_nxt;
        *(uint4*)&Bs[row][kq] = b_nxt;
        if (k0 + 32 < K) {
            a_nxt = loadA(k0 + 32);
            b_nxt = *(const uint4*)(bptr + k0 + 32);
        }
        __syncthreads();
        bf16x8 af0 = *(const bf16x8*)&As[wr + l16][lk8];
        bf16x8 af1 = *(const bf16x8*)&As[wr + 16 + l16][lk8];
        bf16x8 bf0 = *(const bf16x8*)&Bs[wc + l16][lk8];
        bf16x8 bf1 = *(const bf16x8*)&Bs[wc + 16 + l16][lk8];
        acc00 = __builtin_amdgcn_mfma_f32_16x16x32_bf16(af0, bf0, acc00, 0, 0, 0);
        acc01 = __builtin_amdgcn_mfma_f32_16x16x32_bf16(af0, bf1, acc01, 0, 0, 0);
        acc10 = __builtin_amdgcn_mfma_f32_16x16x32_bf16(af1, bf0, acc10, 0, 0, 0);
        acc11 = __builtin_amdgcn_mfma_f32_16x16x32_bf16(af1, bf1, acc11, 0, 0, 0);
    }

#define EPI_FRAG(ACC, MF, NF)                                                  \
    {                                                                          \
        const int gcol = n0 + wc + (NF)*16 + l16;                              \
        const float bv = bias ? bias[gcol] : 0.f;                              \
        float v_[4];                                                           \
        _Pragma("unroll")                                                      \
        for (int r = 0; r < 4; r++) {                                          \
            float v = ACC[r] + bv;                                             \
            if (RELU) v = fmaxf(v, 0.f);                                       \
            v_[r] = v;                                                         \
        }                                                                      \
        const int lr0 = wr + (MF)*16 + r4;                                     \
        if (MODE >= 3) {                                                       \
            const int lc = wc + (NF)*16 + l16;                                 \
            _Pragma("unroll")                                                  \
            for (int r = 0; r < 4; r++)                                        \
                Ts[lc][lr0 + r] = (MODE == 3) ? f16bits((f16)v_[r])            \
                                              : f2bf(v_[r]);                   \
        } else {                                                               \
            _Pragma("unroll")                                                  \
            for (int r = 0; r < 4; r++) {                                      \
                const size_t off = (size_t)(m0 + lr0 + r) * ldc + gcol;        \
                if (MODE == 0) ((float*)C)[off] = v_[r];                       \
                else if (MODE == 1) ((u16*)C)[off] = f2bf(v_[r]);              \
                else ((u16*)C)[off] = f16bits((f16)v_[r]);                     \
            }                                                                  \
        }                                                                      \
    }
    EPI_FRAG(acc00, 0, 0) EPI_FRAG(acc01, 0, 1)
    EPI_FRAG(acc10, 1, 0) EPI_FRAG(acc11, 1, 1)
#undef EPI_FRAG

    if (MODE >= 3) {
        // coalesced write of the 64(m->s) x 64(n->h) tile into C[h][128]
        __syncthreads();
        u16* cb = (u16*)C + (size_t)(m0 >> 7) * ((size_t)ldc * 128) + (m0 & 127);
#pragma unroll
        for (int u = 0; u < 4; u++) {
            const int i = tid + u * 256;
            const int hl = i >> 4;
            const int s4 = (i & 15) << 2;
            ushort4 o;
            o.x = Ts[hl][s4 + 0]; o.y = Ts[hl][s4 + 1];
            o.z = Ts[hl][s4 + 2]; o.w = Ts[hl][s4 + 3];
            *(ushort4*)(cb + (size_t)(n0 + hl) * 128 + s4) = o;
        }
    }
}

// ---------------------------------------------------------------------------
// K0: weight transpose+convert. grid 8064.
// ---------------------------------------------------------------------------
__global__ __launch_bounds__(256) void prep_kernel(
    const float* __restrict__ W1, const float* __restrict__ Wf1,
    const float* __restrict__ Wf2,
    u16* __restrict__ w1t, u16* __restrict__ wf1t, u16* __restrict__ wf2t)
{
    const int tid = threadIdx.x;
    int bid = blockIdx.x;
    const float* in; u16* outp; int tx, ty;
    if (bid < 4608) {
        const int z = bid / 1152, r = bid % 1152;
        tx = r % 24; ty = r / 24;
        in = W1 + (size_t)z * 1536 * 768; outp = w1t + (size_t)z * 768 * 1536;
    } else if (bid < 6912) {
        const int r = bid - 4608;
        tx = r % 48; ty = r / 48;
        in = Wf1; outp = wf1t;
    } else {
        const int r = bid - 6912;
        tx = r % 24; ty = r / 24;
        in = Wf2; outp = wf2t;
    }
    const int C = (bid >= 4608 && bid < 6912) ? 1536 : 768;
    const int c0 = tx * 32, r0 = ty * 32;
    __shared__ float tile[32][33];
    const int tr = tid >> 3, tc = (tid & 7) << 2;
    float4 v = *(const float4*)(in + (size_t)(r0 + tr) * C + c0 + tc);
    tile[tr][tc] = v.x; tile[tr][tc + 1] = v.y;
    tile[tr][tc + 2] = v.z; tile[tr][tc + 3] = v.w;
    __syncthreads();
    ushort4 o;
    o.x = f2bf(tile[tc + 0][tr]); o.y = f2bf(tile[tc + 1][tr]);
    o.z = f2bf(tile[tc + 2][tr]); o.w = f2bf(tile[tc + 3][tr]);
    *(ushort4*)(outp + (size_t)(c0 + tr) * 1536 + r0 + tc) = o;
}

// ---------------------------------------------------------------------------
// K1: sx + py_t + PW_t batched. 1D grid 960. ONE unioned smem buffer.
// ---------------------------------------------------------------------------
__global__ __launch_bounds__(256) void sxpypw_kernel(
    const float* __restrict__ sp, const float* __restrict__ ph,
    const u16* __restrict__ w1t, const u16* __restrict__ wf1t,
    const float* __restrict__ b1,
    u16* __restrict__ sxf, u16* __restrict__ pyt, u16* __restrict__ pwt)
{
    __shared__ __align__(16) char smem[GEMM_SMEM];
    int job = blockIdx.x;
    if (job < 384) {
        const int n = job / 96, r = job % 96, my = r / 12, nx = r % 12;
        gemm_mfma_body<false, 2, true>(sp, 768,
            w1t + (size_t)n * 768 * 1536, 1536, b1 + n * HD_,
            sxf + (size_t)n * M_ * HD_, HD_, 768, my * 64, nx * 64, smem);
    } else if (job < 768) {
        const int j = job - 384;
        const int n = j / 96, r = j % 96, my = r / 12, nx = r % 12;
        gemm_mfma_body<false, 3, true>(ph, 768,
            w1t + (size_t)n * 768 * 1536 + 768, 1536, nullptr,
            pyt + (size_t)n * 4 * 768 * 128, 768, 768, my * 64, nx * 64, smem);
    } else {
        const int j = job - 768;
        const int b = j / 48, r = j % 48, my = r / 24, nx = r % 24;
        gemm_mfma_body<false, 4, true>(ph + (size_t)b * 128 * 768, 768,
            wf1t + 768, 1536, nullptr,
            pwt + (size_t)b * 1536 * 128, 1536, 768, my * 64, nx * 64, smem);
    }
}

// ---------------------------------------------------------------------------
// K2: scores + softmax — PROVEN r2 geometry: block=(n,b,t8), 4 waves lockstep
// on ONE py panel (L1 sharing), each wave 2 t-rows. Writes 0.25-scaled probs.
// ---------------------------------------------------------------------------
__global__ __launch_bounds__(256) void scores_softmax_kernel(
    const u16* __restrict__ sxf,     // f16 [n][512][768]
    const u16* __restrict__ pyt,     // f16 [n][b][768][128]
    const float* __restrict__ w2,    // f32 [n][768]
    float* __restrict__ probs)       // f32 [n][512][128]
{
    const int bid = blockIdx.x;
    const int n = bid >> 6, b = (bid >> 4) & 3, t0 = (bid & 15) * 8;
    const int tid = threadIdx.x, lane = tid & 63, w = tid >> 6;

    __shared__ __align__(16) f16x2 sxs[8][768];
    __shared__ __align__(16) f16x2 w2s[768];

    for (int q = 0; q < 6; q++) {
        const int u = tid + q * 256;
        const int r = u / 192;
        const int h4 = (u % 192) * 4;
        ushort4 v = *(const ushort4*)(sxf + ((size_t)(n * 512 + b * 128 + t0 + r)) * 768 + h4);
        sxs[r][h4 + 0] = bcast2(splat2(v.x));
        sxs[r][h4 + 1] = bcast2(splat2(v.y));
        sxs[r][h4 + 2] = bcast2(splat2(v.z));
        sxs[r][h4 + 3] = bcast2(splat2(v.w));
    }
    for (int q = 0; q < 3; q++) {
        const int i = tid + q * 256;
        w2s[i] = bcast2(splat2(f16bits((f16)w2[n * 768 + i])));
    }
    __syncthreads();

    const f16x2* pypanel = (const f16x2*)(pyt + ((size_t)((n << 2) | b)) * 768 * 128) + lane;
    const f16x2 z2 = {(f16)0, (f16)0};

    float accA0 = 0.f, accA1 = 0.f, accB0 = 0.f, accB1 = 0.f;
    const int rA = 2 * w, rB = 2 * w + 1;

    f16x2 b0[16], b1[16];
#pragma unroll
    for (int j = 0; j < 16; j++) b0[j] = pypanel[(size_t)j * 64];
#pragma unroll
    for (int j = 0; j < 16; j++) b1[j] = pypanel[(size_t)(16 + j) * 64];

    auto compute = [&](const f16x2 (&buf)[16], int hbase) {
        f16x2 aA = z2, aB = z2;
#pragma unroll
        for (int j4 = 0; j4 < 16; j4 += 4) {
            uint4 sau = *(const uint4*)&sxs[rA][hbase + j4];
            uint4 sbu = *(const uint4*)&sxs[rB][hbase + j4];
            uint4 wvu = *(const uint4*)&w2s[hbase + j4];
            const u32 sa_[4] = {sau.x, sau.y, sau.z, sau.w};
            const u32 sb_[4] = {sbu.x, sbu.y, sbu.z, sbu.w};
            const u32 wv_[4] = {wvu.x, wvu.y, wvu.z, wvu.w};
#pragma unroll
            for (int j = 0; j < 4; j++) {
                const f16x2 pv = buf[j4 + j];
                const f16x2 wj = bcast2(wv_[j]);
                f16x2 ra = __builtin_elementwise_max(bcast2(sa_[j]) + pv, z2);
                f16x2 rb = __builtin_elementwise_max(bcast2(sb_[j]) + pv, z2);
                aA = __builtin_elementwise_fma(ra, wj, aA);
                aB = __builtin_elementwise_fma(rb, wj, aB);
            }
        }
        accA0 += (float)aA.x; accA1 += (float)aA.y;
        accB0 += (float)aB.x; accB1 += (float)aB.y;
    };

    for (int hc = 0; hc < 768; hc += 32) {
        compute(b0, hc);
        if (hc + 32 < 768) {
#pragma unroll
            for (int j = 0; j < 16; j++) b0[j] = pypanel[(size_t)(hc + 32 + j) * 64];
        }
        compute(b1, hc + 16);
        if (hc + 48 < 768) {
#pragma unroll
            for (int j = 0; j < 16; j++) b1[j] = pypanel[(size_t)(hc + 48 + j) * 64];
        }
    }

#pragma unroll
    for (int which = 0; which < 2; which++) {
        const float s0 = which ? accB0 : accA0;
        const float s1 = which ? accB1 : accA1;
        const int t = t0 + 2 * w + which;
        float mx = fmaxf(s0, s1);
#pragma unroll
        for (int off = 32; off; off >>= 1) mx = fmaxf(mx, __shfl_xor(mx, off, 64));
        const float e0 = expf(s0 - mx), e1 = expf(s1 - mx);
        float sm = e0 + e1;
#pragma unroll
        for (int off = 32; off; off >>= 1) sm += __shfl_xor(sm, off, 64);
        const float inv = 0.25f / sm;
        float2 pr; pr.x = e0 * inv; pr.y = e1 * inv;
        *(float2*)&probs[((size_t)(n * 512 + b * 128 + t)) * 128 + 2 * lane] = pr;
    }
}

// ---------------------------------------------------------------------------
// K3: FFN1' : hbuf = relu(speech @ Wf1_top + attn @ PW[b] + bf1), K=896.
// attn rows (k>=768) summed from the 4 heads' probs during staging. grid (24,8).
// ---------------------------------------------------------------------------
__global__ __launch_bounds__(256) void gemm_ffn1_kernel(
    const float* __restrict__ speech, const float* __restrict__ probs,
    const u16* __restrict__ wf1t, const u16* __restrict__ pwt,
    const float* __restrict__ bf1, u16* __restrict__ hbuf)
{
    __shared__ __align__(16) u16 As[64][40];
    __shared__ __align__(16) u16 Bs[64][40];

    const int tid = threadIdx.x;
    const int row = tid >> 2;
    const int kq  = (tid & 3) << 3;
    const int lane = tid & 63;
    const int w  = tid >> 6;
    const int wr = (w >> 1) << 5;
    const int wc = (w & 1) << 5;
    const int l16 = lane & 15;
    const int lk8 = (lane >> 4) << 3;
    const int r4  = (lane >> 4) << 2;

    const int m0 = blockIdx.y * 64, n0 = blockIdx.x * 64;
    const int b = m0 >> 7;

    const float* arow = speech + (size_t)(m0 + row) * 768 + kq;
    const float* prow = probs + (size_t)(m0 + row) * 128 + kq;
    const u16* brow_w = wf1t + (size_t)(n0 + row) * 1536 + kq;
    const u16* brow_p = pwt + (size_t)b * 1536 * 128 + (size_t)(n0 + row) * 128 + kq;

    f32x4 acc00 = {0.f,0.f,0.f,0.f}, acc01 = {0.f,0.f,0.f,0.f};
    f32x4 acc10 = {0.f,0.f,0.f,0.f}, acc11 = {0.f,0.f,0.f,0.f};

    auto loadA = [&](int k0) -> uint4 {
        uint4 r;
        if (k0 < 768) {
            float4 ax = *(const float4*)(arow + k0);
            float4 ay = *(const float4*)(arow + k0 + 4);
            r.x = pack_bf2(ax.x, ax.y); r.y = pack_bf2(ax.z, ax.w);
            r.z = pack_bf2(ay.x, ay.y); r.w = pack_bf2(ay.z, ay.w);
        } else {
            const int ko = k0 - 768;
            float4 ax = make_float4(0.f, 0.f, 0.f, 0.f), ay = ax;
#pragma unroll
            for (int n = 0; n < 4; n++) {
                float4 u0 = *(const float4*)(prow + (size_t)n * 512 * 128 + ko);
                float4 u1 = *(const float4*)(prow + (size_t)n * 512 * 128 + ko + 4);
                ax.x += u0.x; ax.y += u0.y; ax.z += u0.z; ax.w += u0.w;
                ay.x += u1.x; ay.y += u1.y; ay.z += u1.z; ay.w += u1.w;
            }
            r.x = pack_bf2(ax.x, ax.y); r.y = pack_bf2(ax.z, ax.w);
            r.z = pack_bf2(ay.x, ay.y); r.w = pack_bf2(ay.z, ay.w);
        }
        return r;
    };
    auto loadB = [&](int k0) -> uint4 {
        if (k0 < 768) return *(const uint4*)(brow_w + k0);
        return *(const uint4*)(brow_p + (k0 - 768));
    };

    uint4 a_nxt = loadA(0);
    uint4 b_nxt = loadB(0);

    for (int k0 = 0; k0 < 896; k0 += 32) {
        __syncthreads();
        *(uint4*)&As[row][kq] = a_nxt;
        *(uint4*)&Bs[row][kq] = b_nxt;
        if (k0 + 32 < 896) {
            a_nxt = loadA(k0 + 32);
            b_nxt = loadB(k0 + 32);
        }
        __syncthreads();
        bf16x8 af0 = *(const bf16x8*)&As[wr + l16][lk8];
        bf16x8 af1 = *(const bf16x8*)&As[wr + 16 + l16][lk8];
        bf16x8 bf0 = *(const bf16x8*)&Bs[wc + l16][lk8];
        bf16x8 bf1 = *(const bf16x8*)&Bs[wc + 16 + l16][lk8];
        acc00 = __builtin_amdgcn_mfma_f32_16x16x32_bf16(af0, bf0, acc00, 0, 0, 0);
        acc01 = __builtin_amdgcn_mfma_f32_16x16x32_bf16(af0, bf1, acc01, 0, 0, 0);
        acc10 = __builtin_amdgcn_mfma_f32_16x16x32_bf16(af1, bf0, acc10, 0, 0, 0);
        acc11 = __builtin_amdgcn_mfma_f32_16x16x32_bf16(af1, bf1, acc11, 0, 0, 0);
    }

#define EPI_FFN1(ACC, MF, NF)                                                  \
    {                                                                          \
        const int gcol = n0 + wc + (NF)*16 + l16;                              \
        const float bv = bf1[gcol];                                            \
        const int lr0 = wr + (MF)*16 + r4;                                     \
        _Pragma("unroll")                                                      \
        for (int r = 0; r < 4; r++) {                                          \
            float v = fmaxf(ACC[r] + bv, 0.f);                                 \
            hbuf[(size_t)(m0 + lr0 + r) * 1536 + gcol] = f2bf(v);              \
        }                                                                      \
    }
    EPI_FFN1(acc00, 0, 0) EPI_FFN1(acc01, 0, 1)
    EPI_FFN1(acc10, 1, 0) EPI_FFN1(acc11, 1, 1)
#undef EPI_FFN1
}

// K4: FFN2: outpre = hbuf @ Wf2 + bf2, f32 out. grid (12,8)
__global__ __launch_bounds__(256) void gemm_ffn2_kernel(
    const u16* __restrict__ hbuf, const u16* __restrict__ wf2t,
    const float* __restrict__ bf2, float* __restrict__ outpre)
{
    __shared__ __align__(16) char smem[GEMM_SMEM];
    gemm_mfma_body<false, 0, false>(hbuf, 1536, wf2t, 1536, bf2,
                                    outpre, 768, 1536,
                                    blockIdx.y * 64, blockIdx.x * 64, smem);
}

// K5: fused LN stats + time-mean. grid 12 = (b, 256-d chunk).
__global__ __launch_bounds__(256) void ln_fused_kernel(
    const float* __restrict__ x, const float* __restrict__ g,
    const float* __restrict__ lb, float* __restrict__ out)
{
    const int b = blockIdx.x / 3, c = blockIdx.x % 3;
    const int tid = threadIdx.x, lane = tid & 63, w = tid >> 6;
    __shared__ float rs[T1_];
    __shared__ float Sred[4];

    float prsum = 0.f;
    for (int i = 0; i < 32; i++) {
        const int row = w * 32 + i;
        const float4* x4 = (const float4*)(x + ((size_t)(b * T1_ + row)) * D_);
        float s = 0.f, ss = 0.f;
#pragma unroll
        for (int j = 0; j < 3; j++) {
            float4 v = x4[j * 64 + lane];
            s += v.x + v.y + v.z + v.w;
            ss += v.x * v.x + v.y * v.y + v.z * v.z + v.w * v.w;
        }
#pragma unroll
        for (int off = 32; off; off >>= 1) {
            s += __shfl_xor(s, off, 64);
            ss += __shfl_xor(ss, off, 64);
        }
        if (lane == 0) {
            const float mu = s * (1.f / D_);
            const float var = ss * (1.f / D_) - mu * mu;
            const float r = rsqrtf(var + LN_EPS_);
            rs[row] = r;
            prsum += mu * r;
        }
    }
    if (lane == 0) Sred[w] = prsum;
    __syncthreads();
    const float S = Sred[0] + Sred[1] + Sred[2] + Sred[3];
    const float* xb = x + (size_t)b * T1_ * D_;
    const int d = c * 256 + tid;
    float acc = 0.f;
#pragma unroll 8
    for (int t = 0; t < T1_; t++)
        acc = fmaf(xb[(size_t)t * D_ + d], rs[t], acc);
    out[b * D_ + d] = g[d] * (acc - S) * (1.f / T1_) + lb[d];
}

extern "C" void kernel_launch(void* const* d_in, const int* in_sizes, int n_in,
                              void* d_out, int out_size, void* d_ws, size_t ws_size,
                              hipStream_t stream)
{
    const float* speech = (const float*)d_in[0];
    const float* phon   = (const float*)d_in[1];
    const float* W1     = (const float*)d_in[2];
    const float* b1     = (const float*)d_in[3];
    const float* w2     = (const float*)d_in[4];
    // d_in[5] = b2: softmax-invariant, unused
    const float* Wf1    = (const float*)d_in[6];
    const float* bf1    = (const float*)d_in[7];
    const float* Wf2    = (const float*)d_in[8];
    const float* bf2    = (const float*)d_in[9];
    const float* ln_g   = (const float*)d_in[10];
    const float* ln_b   = (const float*)d_in[11];
    float* out = (float*)d_out;

    char* w = (char*)d_ws;
    auto alloc = [&](size_t bytes) { char* p = w; w += (bytes + 1023) & ~(size_t)1023; return p; };
    u16* w1t    = (u16*)alloc((size_t)NH_ * 768 * 1536 * 2);
    u16* wf1t   = (u16*)alloc((size_t)1536 * 1536 * 2);
    u16* wf2t   = (u16*)alloc((size_t)768 * 1536 * 2);
    u16* sxf    = (u16*)alloc((size_t)NH_ * M_ * HD_ * 2);        // f16
    u16* pyt    = (u16*)alloc((size_t)NH_ * B_ * 768 * 128 * 2);  // f16 transposed
    u16* pwt    = (u16*)alloc((size_t)B_ * 1536 * 128 * 2);       // bf16 transposed
    float* probs  = (float*)alloc((size_t)NH_ * M_ * T2_ * 4);
    u16* hbuf   = (u16*)alloc((size_t)M_ * 2 * HD_ * 2);
    float* outpre = (float*)alloc((size_t)M_ * D_ * 4);

    hipLaunchKernelGGL(prep_kernel, dim3(8064), dim3(256), 0, stream,
                       W1, Wf1, Wf2, w1t, wf1t, wf2t);
    hipLaunchKernelGGL(sxpypw_kernel, dim3(960), dim3(256), 0, stream,
                       speech, phon, w1t, wf1t, b1, sxf, pyt, pwt);
    hipLaunchKernelGGL(scores_softmax_kernel, dim3(256), dim3(256), 0, stream,
                       sxf, pyt, w2, probs);
    hipLaunchKernelGGL(gemm_ffn1_kernel, dim3(24, 8), dim3(256), 0, stream,
                       speech, probs, wf1t, pwt, bf1, hbuf);
    hipLaunchKernelGGL(gemm_ffn2_kernel, dim3(12, 8), dim3(256), 0, stream,
                       hbuf, wf2t, bf2, outpre);
    hipLaunchKernelGGL(ln_fused_kernel, dim3(12), dim3(256), 0, stream,
                       outpre, ln_g, ln_b, out);
}